// Round 5
// baseline (412.993 us; speedup 1.0000x reference)
//
#include <hip/hip_runtime.h>

// GHM Dice loss, 4 dispatches, zero global atomics, zero per-element LDS ops:
//  k_pass1: quartered-stream partials {I,P,T} (reads p,t,lw as 12 address
//           streams) + packs (t,lw) into 1 byte per float4      [MASK=true]
//  k_mid:   1-block MLP reduce of pws1 -> ws[0]=2I/S, ws[1]=S
//  k_pass2: quartered-stream partials {cnt[10],sm[10],tot} reading p as 4
//           streams + mask words (142 MB instead of 402 MB)     [MASK=true]
//  k_final: 1-block MLP reduce of pws2 -> loss
//
// Round-13 theory: r4 killed the MLP theory (VGPR=104, batch live, BW
// unchanged 3.2 TB/s). The 6-kernel dataset instead fits a per-address-
// stream cap of ~1.0-1.4 TB/s: 2 streams->2.7, 3 streams->3.1-4.3,
// 1 stream (r2 pass2, p+mask)->~2.0. So: split each array into 4 quarters
// and read one float4 from each quarter of each array per iteration ->
// pass1 = 12 concurrent sequential frontiers, pass2 = 5. VALU/load ratio
// unchanged vs r2 (clean isolation of stream count). Mask word now packs
// byte q = quarter-q float4's 8 bits; same 1B/float4 density.
//
// ws float layout:
//   [0]=scale=2I/S  [1]=S                      (written by k_mid)
//   [OFF1 + blk*4 + {0,1,2}]   pws1 {I,P,T}    (slot 3 pad, ignored)
//   [OFF2 + blk*24 + s]        pws2 s=0..9 cnt, 10..19 sm, 20 vcount
//   byte MASK_OFF ..           uint per (chunk,lane): byte q = mask of
//                              float4 at q*nq + c*256 + tid (bits0-3 t,
//                              bits4-7 lw); chunks c < nfullq = (n4/4)/256

constexpr int BINS   = 10;
constexpr int BLOCKS = 2048;             // persistent; nfullq=8192 -> 4 iters/blk
constexpr int OFF1   = 64;
constexpr int OFF2   = 16448;
constexpr size_t MASK_OFF = 266240;      // byte offset of mask words in ws

__device__ __forceinline__ void acc3(const float4& pv, const float4& tv,
                                     float& sI, float& sP, float& sT) {
    sI += pv.x * tv.x + pv.y * tv.y + pv.z * tv.z + pv.w * tv.w;
    sP += pv.x + pv.y + pv.z + pv.w;
    sT += tv.x + tv.y + tv.z + tv.w;
}

__device__ __forceinline__ unsigned mbyte(const float4& tv, const float4& wv) {
    unsigned mb = 0;
    mb |= (tv.x != 0.f) ? 1u   : 0u;  mb |= (tv.y != 0.f) ? 2u   : 0u;
    mb |= (tv.z != 0.f) ? 4u   : 0u;  mb |= (tv.w != 0.f) ? 8u   : 0u;
    mb |= (wv.x != 0.f) ? 16u  : 0u;  mb |= (wv.y != 0.f) ? 32u  : 0u;
    mb |= (wv.z != 0.f) ? 64u  : 0u;  mb |= (wv.w != 0.f) ? 128u : 0u;
    return mb;
}

template<bool MASK>
__global__ __launch_bounds__(256) void k_pass1(const float4* __restrict__ p,
                                               const float4* __restrict__ t,
                                               const float4* __restrict__ lw,
                                               unsigned* __restrict__ maskw,
                                               float* __restrict__ ws,
                                               int n4, int n) {
    const int tid    = threadIdx.x;
    const int G      = gridDim.x;
    const int nq     = n4 >> 2;          // float4s per quarter
    const int nfullq = nq >> 8;          // full 256-float4 chunks per quarter
    float sI = 0.f, sP = 0.f, sT = 0.f;

    if constexpr (MASK) {
        for (int c = blockIdx.x; c < nfullq; c += G) {
            const int b0 = c * 256 + tid;            // within-quarter index
            // 12 address streams: 4 quarters x {p,t,lw}
            float4 p0 = p[b0], p1 = p[b0 + nq], p2 = p[b0 + 2 * nq], p3 = p[b0 + 3 * nq];
            float4 t0 = t[b0], t1 = t[b0 + nq], t2 = t[b0 + 2 * nq], t3 = t[b0 + 3 * nq];
            float4 w0 = lw[b0], w1 = lw[b0 + nq], w2 = lw[b0 + 2 * nq], w3 = lw[b0 + 3 * nq];
            acc3(p0, t0, sI, sP, sT);
            acc3(p1, t1, sI, sP, sT);
            acc3(p2, t2, sI, sP, sT);
            acc3(p3, t3, sI, sP, sT);
            unsigned mw = mbyte(t0, w0) | (mbyte(t1, w1) << 8) |
                          (mbyte(t2, w2) << 16) | (mbyte(t3, w3) << 24);
            maskw[b0] = mw;                          // coalesced word store
        }
    } else {
        for (int c = blockIdx.x; c < nfullq; c += G) {
            const int b0 = c * 256 + tid;
            float4 p0 = p[b0], p1 = p[b0 + nq], p2 = p[b0 + 2 * nq], p3 = p[b0 + 3 * nq];
            float4 t0 = t[b0], t1 = t[b0 + nq], t2 = t[b0 + 2 * nq], t3 = t[b0 + 3 * nq];
            acc3(p0, t0, sI, sP, sT);
            acc3(p1, t1, sI, sP, sT);
            acc3(p2, t2, sI, sP, sT);
            acc3(p3, t3, sI, sP, sT);
        }
    }

    if (blockIdx.x == 0) {               // tails: per-quarter + global + scalar
        for (int q = 0; q < 4; ++q)      // per-quarter float4 tail (nq % 256)
            for (int i = q * nq + nfullq * 256 + tid; i < (q + 1) * nq; i += 256) {
                float4 pv = p[i], tv = t[i];
                acc3(pv, tv, sI, sP, sT);
            }
        for (int i = 4 * nq + tid; i < n4; i += 256) {   // global float4 tail
            float4 pv = p[i], tv = t[i];
            acc3(pv, tv, sI, sP, sT);
        }
        if (tid == 0) {                  // scalar tail (n % 4)
            const float* pf = (const float*)p;
            const float* tf = (const float*)t;
            for (int i = n4 * 4; i < n; ++i) { sI += pf[i] * tf[i]; sP += pf[i]; sT += tf[i]; }
        }
    }
#pragma unroll
    for (int o = 32; o > 0; o >>= 1) {
        sI += __shfl_down(sI, o);
        sP += __shfl_down(sP, o);
        sT += __shfl_down(sT, o);
    }
    __shared__ float rI[4], rP[4], rT[4];
    int wave = tid >> 6, lane = tid & 63;
    if (lane == 0) { rI[wave] = sI; rP[wave] = sP; rT[wave] = sT; }
    __syncthreads();
    if (tid == 0) {                      // plain stores — no atomics
        float* o = &ws[OFF1 + blockIdx.x * 4];
        o[0] = rI[0] + rI[1] + rI[2] + rI[3];
        o[1] = rP[0] + rP[1] + rP[2] + rP[3];
        o[2] = rT[0] + rT[1] + rT[2] + rT[3];
    }
}

// 1-block reduce of pws1 (nb1 records): independent float4 loads + LDS reduce.
__global__ __launch_bounds__(256) void k_mid(float* __restrict__ ws, int nb1) {
    const float4* pws = (const float4*)&ws[OFF1];
    float aI = 0.f, aP = 0.f, aT = 0.f;
    for (int b = threadIdx.x; b < nb1; b += 256) {
        float4 v = pws[b];                            // slot 3 = pad (ignored)
        aI += v.x; aP += v.y; aT += v.z;
    }
    __shared__ float red[256 * 5];
    float* mine = &red[threadIdx.x * 5];              // odd stride: conflict-free
    mine[0] = aI; mine[1] = aP; mine[2] = aT;
    __syncthreads();
    int tid = threadIdx.x;
    if (tid < 3) {
        float s = 0.f;
        for (int i = 0; i < 256; ++i) s += red[i * 5 + tid];
        red[tid] = s;
    }
    __syncthreads();
    if (tid == 0) {
        float I = red[0];
        float S = red[1] + red[2];
        ws[0] = 2.f * I / S;
        ws[1] = S;
    }
}

template<bool MASK>
__global__ __launch_bounds__(256) void k_pass2(const float4* __restrict__ p,
                                               const float4* __restrict__ t,
                                               const float4* __restrict__ lw,
                                               const unsigned* __restrict__ maskw,
                                               float* __restrict__ ws,
                                               int n4, int n) {
    const float scale    = ws[0];        // 2I/S
    const float edge_top = 1.0f + 1e-6f;
    const int tid    = threadIdx.x;
    const int G      = gridDim.x;
    const int nq     = n4 >> 2;
    const int nfullq = nq >> 8;

    // Per-thread register histogram; compile-time indexing -> VGPRs.
    int   cnt[BINS];
    float sm[BINS];
#pragma unroll
    for (int b = 0; b < BINS; ++b) { cnt[b] = 0; sm[b] = 0.f; }
    int vcount = 0;

    auto process = [&](float pe, float te, bool valid) {
        vcount += valid;                          // int addc
        float g = fabsf(scale * pe - te);         // fma; abs folds into consumers
        bool inr = valid && (g < edge_top);
        int b = (int)(g * 10.f);                  // g >= 0, trunc == floor
        b = b > (BINS - 1) ? (BINS - 1) : b;
        int slot = inr ? b : BINS;                // dummy slot 10: no masked adds
        float adds = 2.f * pe * te;
#pragma unroll
        for (int b0 = 0; b0 < BINS; ++b0) {
            bool m = (slot == b0);
            cnt[b0] += m;                         // cmp + addc
            sm[b0]  += m ? adds : 0.f;            // cndmask + add
        }
    };
    auto procq = [&](const float4& q, unsigned b) {
        process(q.x, (b & 1u) ? 1.f : 0.f, (b & 16u)  != 0);
        process(q.y, (b & 2u) ? 1.f : 0.f, (b & 32u)  != 0);
        process(q.z, (b & 4u) ? 1.f : 0.f, (b & 64u)  != 0);
        process(q.w, (b & 8u) ? 1.f : 0.f, (b & 128u) != 0);
    };

    if constexpr (MASK) {
        for (int c = blockIdx.x; c < nfullq; c += G) {
            const int b0 = c * 256 + tid;
            // 5 address streams: 4 p-quarters + mask words
            float4 p0 = p[b0], p1 = p[b0 + nq], p2 = p[b0 + 2 * nq], p3 = p[b0 + 3 * nq];
            unsigned mw = maskw[b0];
            procq(p0, mw);
            procq(p1, mw >> 8);
            procq(p2, mw >> 16);
            procq(p3, mw >> 24);
        }
    } else {
        for (int c = blockIdx.x; c < nfullq; c += G) {
            const int b0 = c * 256 + tid;
#pragma unroll
            for (int q = 0; q < 4; ++q) {
                float4 pv = p[b0 + q * nq], tv = t[b0 + q * nq], wv = lw[b0 + q * nq];
                process(pv.x, tv.x, wv.x > 0.f);
                process(pv.y, tv.y, wv.y > 0.f);
                process(pv.z, tv.z, wv.z > 0.f);
                process(pv.w, tv.w, wv.w > 0.f);
            }
        }
    }

    if (blockIdx.x == 0) {               // tails with direct t,lw reads
        for (int q = 0; q < 4; ++q)
            for (int i = q * nq + nfullq * 256 + tid; i < (q + 1) * nq; i += 256) {
                float4 pv = p[i], tv = t[i], wv = lw[i];
                process(pv.x, tv.x, wv.x > 0.f);
                process(pv.y, tv.y, wv.y > 0.f);
                process(pv.z, tv.z, wv.z > 0.f);
                process(pv.w, tv.w, wv.w > 0.f);
            }
        for (int i = 4 * nq + tid; i < n4; i += 256) {
            float4 pv = p[i], tv = t[i], wv = lw[i];
            process(pv.x, tv.x, wv.x > 0.f);
            process(pv.y, tv.y, wv.y > 0.f);
            process(pv.z, tv.z, wv.z > 0.f);
            process(pv.w, tv.w, wv.w > 0.f);
        }
        if (tid == 0) {                  // scalar tail (n % 4)
            const float* pf = (const float*)p;
            const float* tf = (const float*)t;
            const float* wf = (const float*)lw;
            for (int i = n4 * 4; i < n; ++i) process(pf[i], tf[i], wf[i] > 0.f);
        }
    }

    // Block reduction: LDS transpose, odd stride 21 -> free 2-lane/bank aliasing.
    __shared__ float red[256 * 21];
    float* mine = &red[tid * 21];
#pragma unroll
    for (int b0 = 0; b0 < BINS; ++b0) {
        mine[b0]        = (float)cnt[b0];
        mine[BINS + b0] = sm[b0];
    }
    mine[2 * BINS] = (float)vcount;
    __syncthreads();

    if (tid < 2 * BINS + 1) {
        float v = 0.f;
        for (int i = 0; i < 256; ++i) v += red[i * 21 + tid];
        ws[OFF2 + blockIdx.x * 24 + tid] = v;   // plain store — no atomics
    }
}

// 1-block reduce of pws2: 24-float records = 6 aligned float4s, 6 independent
// loads per record per thread, then LDS transpose. Pad slots discarded.
__global__ __launch_bounds__(256) void k_final(const float* __restrict__ ws,
                                               float* __restrict__ out, int nb2) {
    float acc[24];
#pragma unroll
    for (int s = 0; s < 24; ++s) acc[s] = 0.f;

    for (int b = threadIdx.x; b < nb2; b += 256) {
        const float4* rec = (const float4*)&ws[OFF2 + b * 24];
        float4 v0 = rec[0], v1 = rec[1], v2 = rec[2],
               v3 = rec[3], v4 = rec[4], v5 = rec[5];
        acc[0]  += v0.x; acc[1]  += v0.y; acc[2]  += v0.z; acc[3]  += v0.w;
        acc[4]  += v1.x; acc[5]  += v1.y; acc[6]  += v1.z; acc[7]  += v1.w;
        acc[8]  += v2.x; acc[9]  += v2.y; acc[10] += v2.z; acc[11] += v2.w;
        acc[12] += v3.x; acc[13] += v3.y; acc[14] += v3.z; acc[15] += v3.w;
        acc[16] += v4.x; acc[17] += v4.y; acc[18] += v4.z; acc[19] += v4.w;
        acc[20] += v5.x;  // 21..23 pad — not accumulated
    }

    __shared__ float red[256 * 25];                  // odd stride: conflict-free
    float* mine = &red[threadIdx.x * 25];
#pragma unroll
    for (int s = 0; s <= 2 * BINS; ++s) mine[s] = acc[s];
    __syncthreads();

    __shared__ float fin[24];
    int tid = threadIdx.x;
    if (tid <= 2 * BINS) {
        float s = 0.f;
        for (int i = 0; i < 256; ++i) s += red[i * 25 + tid];
        fin[tid] = s;
    }
    __syncthreads();
    if (tid == 0) {
        float S   = ws[1];
        float tot = fmaxf(fin[20], 1.0f);
        int nne = 0;
        for (int b = 0; b < BINS; ++b) nne += (fin[b] > 0.f) ? 1 : 0;
        float nn = fmaxf((float)nne, 1.0f);
        float wsum = 0.f;
        for (int b = 0; b < BINS; ++b) {
            float c = fmaxf(fin[b], 1.0f);
            wsum += fin[BINS + b] * (tot / c);   // fin[10+b] carries sum of 2*p*t
        }
        wsum /= nn;
        out[0] = 1.0f - wsum / S;
    }
}

extern "C" void kernel_launch(void* const* d_in, const int* in_sizes, int n_in,
                              void* d_out, int out_size, void* d_ws, size_t ws_size,
                              hipStream_t stream) {
    const float* p  = (const float*)d_in[0];
    const float* t  = (const float*)d_in[1];
    const float* lw = (const float*)d_in[2];
    float* ws  = (float*)d_ws;
    float* out = (float*)d_out;
    int n  = in_sizes[0];
    int n4 = n >> 2;

    unsigned* maskw = (unsigned*)((char*)d_ws + MASK_OFF);
    // mask bytes needed = 4 * nfullq * 256 <= n4
    const bool use_mask = ws_size >= MASK_OFF + (size_t)n4;

    if (use_mask) {
        k_pass1<true><<<BLOCKS, 256, 0, stream>>>((const float4*)p, (const float4*)t,
                                                  (const float4*)lw, maskw, ws, n4, n);
        k_mid<<<1, 256, 0, stream>>>(ws, BLOCKS);
        k_pass2<true><<<BLOCKS, 256, 0, stream>>>((const float4*)p, (const float4*)t,
                                                  (const float4*)lw, maskw, ws, n4, n);
        k_final<<<1, 256, 0, stream>>>(ws, out, BLOCKS);
    } else {
        k_pass1<false><<<BLOCKS, 256, 0, stream>>>((const float4*)p, (const float4*)t,
                                                   (const float4*)lw, maskw, ws, n4, n);
        k_mid<<<1, 256, 0, stream>>>(ws, BLOCKS);
        k_pass2<false><<<BLOCKS, 256, 0, stream>>>((const float4*)p, (const float4*)t,
                                                   (const float4*)lw, maskw, ws, n4, n);
        k_final<<<1, 256, 0, stream>>>(ws, out, BLOCKS);
    }
}